// Round 3
// baseline (2835.299 us; speedup 1.0000x reference)
//
#include <hip/hip_runtime.h>

typedef __bf16 bf16;
typedef __bf16 bf16x8 __attribute__((ext_vector_type(8)));
typedef float  f32x4  __attribute__((ext_vector_type(4)));

#define EPSF 1e-5f

__device__ __forceinline__ float bf2f(bf16 x) { return (float)x; }
__device__ __forceinline__ bf16  f2bf(float x) { return (bf16)x; }
__device__ __forceinline__ float siluf(float x) { return x / (1.f + expf(-x)); }

// ---------------------------------------------------------------------------
// Split-bf16 MFMA GEMM: C[M,N] = A[M,K] @ W[K,N] + bias, A and W f32.
// Each operand is split v = hi + lo (hi = bf16(v), lo = bf16(v - hi));
// acc += aHi*bHi + aHi*bLo + aLo*bHi  (lo*lo dropped, rel err ~2^-16).
// Tile 128(M) x 64(N), BK=32, 256 thr = 4 waves (2M x 2N), each 64x32 via
// 4x2 frags of 16x16x32. M % 128 == 0; K % 32 == 0.
// ---------------------------------------------------------------------------
__global__ __launch_bounds__(256) void gemm_split(
    const float* __restrict__ A, int lda,
    const float* __restrict__ W, int ldw,
    const float* __restrict__ bias,
    int N, int K,
    float* __restrict__ outF, int ldF,
    bf16* __restrict__ outB, int ldB,
    int doGelu)
{
    __shared__ bf16 As [128][40];
    __shared__ bf16 Als[128][40];
    __shared__ bf16 Bs [64][40];
    __shared__ bf16 Bls[64][40];

    const int tid  = threadIdx.x;
    const int lane = tid & 63;
    const int wid  = tid >> 6;
    const int waveM = wid & 1, waveN = wid >> 1;
    const int m16 = lane & 15, quad = lane >> 4;
    const int row0 = blockIdx.x * 128;
    const int n0   = blockIdx.y * 64;

    f32x4 acc[4][2];
#pragma unroll
    for (int i = 0; i < 4; ++i)
#pragma unroll
        for (int j = 0; j < 2; ++j)
            acc[i][j] = (f32x4){0.f, 0.f, 0.f, 0.f};

    const int ar = tid >> 1, akc = (tid & 1) * 16;  // A staging: row, k-chunk
    const int bn = tid & 63, bk0 = tid >> 6;        // B staging: n, k base
    const bool nok = (n0 + bn) < N;

    for (int k0 = 0; k0 < K; k0 += 32) {
        // stage A tile 128x32 (f32 -> hi/lo bf16)
        {
            const float* asrc = A + (size_t)(row0 + ar) * lda + k0 + akc;
            bf16* dh = &As [ar][akc];
            bf16* dl = &Als[ar][akc];
#pragma unroll
            for (int c = 0; c < 4; ++c) {
                float4 f = ((const float4*)asrc)[c];
#pragma unroll
                for (int e = 0; e < 4; ++e) {
                    float v = (&f.x)[e];
                    bf16 hi = f2bf(v);
                    dh[c * 4 + e] = hi;
                    dl[c * 4 + e] = f2bf(v - bf2f(hi));
                }
            }
        }
        // stage B tile 32x64 (f32 strided -> hi/lo bf16, transposed Bs[n][k])
        {
            const float* wsrc = W + (size_t)k0 * ldw + n0 + bn;
#pragma unroll
            for (int it = 0; it < 8; ++it) {
                int k_l = bk0 + it * 4;
                float v = 0.f;
                if (nok) v = wsrc[(size_t)k_l * ldw];
                bf16 hi = f2bf(v);
                Bs [bn][k_l] = hi;
                Bls[bn][k_l] = f2bf(v - bf2f(hi));
            }
        }
        __syncthreads();

        bf16x8 aH[4], aL[4], bH[2], bL[2];
#pragma unroll
        for (int mi = 0; mi < 4; ++mi) {
            aH[mi] = *(const bf16x8*)&As [waveM * 64 + mi * 16 + m16][quad * 8];
            aL[mi] = *(const bf16x8*)&Als[waveM * 64 + mi * 16 + m16][quad * 8];
        }
#pragma unroll
        for (int ni = 0; ni < 2; ++ni) {
            bH[ni] = *(const bf16x8*)&Bs [waveN * 32 + ni * 16 + m16][quad * 8];
            bL[ni] = *(const bf16x8*)&Bls[waveN * 32 + ni * 16 + m16][quad * 8];
        }

#pragma unroll
        for (int mi = 0; mi < 4; ++mi)
#pragma unroll
            for (int ni = 0; ni < 2; ++ni) {
                acc[mi][ni] = __builtin_amdgcn_mfma_f32_16x16x32_bf16(
                    aH[mi], bH[ni], acc[mi][ni], 0, 0, 0);
                acc[mi][ni] = __builtin_amdgcn_mfma_f32_16x16x32_bf16(
                    aH[mi], bL[ni], acc[mi][ni], 0, 0, 0);
                acc[mi][ni] = __builtin_amdgcn_mfma_f32_16x16x32_bf16(
                    aL[mi], bH[ni], acc[mi][ni], 0, 0, 0);
            }
        __syncthreads();
    }

    // epilogue: D element (row = quad*4 + r, col = m16)
#pragma unroll
    for (int ni = 0; ni < 2; ++ni) {
        int col = n0 + waveN * 32 + ni * 16 + m16;
        if (col >= N) continue;
        float bv = bias ? bias[col] : 0.f;
#pragma unroll
        for (int mi = 0; mi < 4; ++mi) {
#pragma unroll
            for (int r = 0; r < 4; ++r) {
                int row = row0 + waveM * 64 + mi * 16 + quad * 4 + r;
                float v = acc[mi][ni][r] + bv;
                if (doGelu) v = 0.5f * v * (1.f + erff(v * 0.70710678118654752f));
                if (outB) outB[(size_t)row * ldB + col] = f2bf(v);
                if (outF) outF[(size_t)row * ldF + col] = v;
            }
        }
    }
}

// ---------------------------------------------------------------------------
// Causal depthwise conv (K=4) + bias + silu over xBC = zx[:, 512:1088].
// Routes: ch<512 -> xs (f32), ch<544 -> B (f32), else C (f32).
// ---------------------------------------------------------------------------
__global__ __launch_bounds__(192) void conv_kernel(
    const bf16* __restrict__ zx,     // 32768 x 1104
    const float* __restrict__ cw,    // 576 x 4
    const float* __restrict__ cb,    // 576
    float* __restrict__ xs,          // 32768 x 512
    float* __restrict__ Bc,          // 32768 x 32
    float* __restrict__ Cc)          // 32768 x 32
{
    int row = blockIdx.x;
    int ch  = blockIdx.y * 192 + threadIdx.x;   // 0..575
    int l   = row & 2047;
    float acc = cb[ch];
#pragma unroll
    for (int i = 0; i < 4; ++i) {
        int ls = l + i - 3;
        if (ls >= 0)
            acc += bf2f(zx[(size_t)(row + i - 3) * 1104 + 512 + ch]) * cw[ch * 4 + i];
    }
    float s = siluf(acc);
    if (ch < 512)      xs[(size_t)row * 512 + ch]        = s;
    else if (ch < 544) Bc[(size_t)row * 32 + (ch - 512)] = s;
    else               Cc[(size_t)row * 32 + (ch - 544)] = s;
}

// ---------------------------------------------------------------------------
// Exact-f32 dt projection: dtraw = h[row,:] @ inw[:,1088+hh] + inb + dtb,
// dt = softplus(dtraw), dA = exp(dt * -exp(Alog)). All f32.
// block = 256 = 16 heads x 16 k-groups, one row per block.
// ---------------------------------------------------------------------------
__global__ __launch_bounds__(256) void dtproj_kernel(
    const float* __restrict__ h,      // 32768 x 256
    const float* __restrict__ inw,    // 256 x 1104
    const float* __restrict__ inb,    // 1104
    const float* __restrict__ dtbp,   // 16
    const float* __restrict__ Alog,   // 16
    float* __restrict__ dtf,          // 32768 x 16
    float* __restrict__ dAf)          // 32768 x 16
{
    __shared__ float wl[256][16];
    __shared__ float hl[256];
    __shared__ float red[16][17];
    int tid = threadIdx.x;
    int row = blockIdx.x;

    {
        const float* src = inw + (size_t)tid * 1104 + 1088;
        *(float4*)&wl[tid][0]  = ((const float4*)src)[0];
        *(float4*)&wl[tid][4]  = ((const float4*)src)[1];
        *(float4*)&wl[tid][8]  = ((const float4*)src)[2];
        *(float4*)&wl[tid][12] = ((const float4*)src)[3];
    }
    if (tid < 64)
        *(float4*)&hl[tid * 4] = *(const float4*)(h + (size_t)row * 256 + tid * 4);
    __syncthreads();

    int hh = tid >> 4, g = tid & 15;
    float s = 0.f;
#pragma unroll
    for (int i = 0; i < 16; ++i) {
        int k = g * 16 + i;
        s += hl[k] * wl[k][hh];
    }
    red[hh][g] = s;
    __syncthreads();

    if (tid < 16) {
        float tot = inb[1088 + tid];
#pragma unroll
        for (int i = 0; i < 16; ++i) tot += red[tid][i];
        float xx = tot + dtbp[tid];
        float sp = (xx > 20.f) ? xx : log1pf(expf(xx));
        float A  = -expf(Alog[tid]);
        dtf[(size_t)row * 16 + tid] = sp;
        dAf[(size_t)row * 16 + tid] = expf(sp * A);
    }
}

// ---------------------------------------------------------------------------
// Sequential SSM scan. One wave per (b, head): lane p = lane&31 (headdim),
// half = lane>>5 covers n in [16*half, 16*half+16). 16 f32 states per lane.
// Register double-buffer: load t+1 while computing t.
// ---------------------------------------------------------------------------
struct StepData { float Bv[16]; float Cv[16]; float da, dtv, xv; };

__device__ __forceinline__ void load_step(
    StepData& S, const float* Bc, const float* Cc,
    const float* dtf, const float* dAf, const float* xs,
    size_t r, int h, int p, int nb)
{
    const float4* bp = (const float4*)(Bc + r * 32 + nb);
    *(float4*)&S.Bv[0]  = bp[0];
    *(float4*)&S.Bv[4]  = bp[1];
    *(float4*)&S.Bv[8]  = bp[2];
    *(float4*)&S.Bv[12] = bp[3];
    const float4* cp = (const float4*)(Cc + r * 32 + nb);
    *(float4*)&S.Cv[0]  = cp[0];
    *(float4*)&S.Cv[4]  = cp[1];
    *(float4*)&S.Cv[8]  = cp[2];
    *(float4*)&S.Cv[12] = cp[3];
    S.da  = dAf[r * 16 + h];
    S.dtv = dtf[r * 16 + h];
    S.xv  = xs[r * 512 + h * 32 + p];
}

__global__ __launch_bounds__(64) void scan_kernel(
    const float* __restrict__ xs,   // 32768 x 512
    const float* __restrict__ Bc,   // 32768 x 32
    const float* __restrict__ Cc,   // 32768 x 32
    const float* __restrict__ dtf,  // 32768 x 16
    const float* __restrict__ dAf,  // 32768 x 16
    const float* __restrict__ Dv,   // 16
    bf16* __restrict__ y)           // 32768 x 512
{
    int bh = blockIdx.x;
    int b = bh >> 4, h = bh & 15;
    int lane = threadIdx.x;
    int p = lane & 31, half = lane >> 5, nb = half * 16;
    float Dh = Dv[h];
    float hs[16];
#pragma unroll
    for (int j = 0; j < 16; ++j) hs[j] = 0.f;
    size_t rb = (size_t)b * 2048;

    StepData S0, S1;
    load_step(S0, Bc, Cc, dtf, dAf, xs, rb, h, p, nb);

    for (int t = 0; t < 2048; t += 2) {
        load_step(S1, Bc, Cc, dtf, dAf, xs, rb + t + 1, h, p, nb);
        {
            float dtx = S0.dtv * S0.xv;
            float da  = S0.da;
            float yv  = 0.f;
#pragma unroll
            for (int j = 0; j < 16; ++j) {
                hs[j] = fmaf(hs[j], da, dtx * S0.Bv[j]);
                yv = fmaf(hs[j], S0.Cv[j], yv);
            }
            yv += __shfl_xor(yv, 32);
            if (half == 0)
                y[(rb + t) * 512 + h * 32 + p] = f2bf(yv + Dh * S0.xv);
        }
        if (t + 2 < 2048)
            load_step(S0, Bc, Cc, dtf, dAf, xs, rb + t + 2, h, p, nb);
        {
            float dtx = S1.dtv * S1.xv;
            float da  = S1.da;
            float yv  = 0.f;
#pragma unroll
            for (int j = 0; j < 16; ++j) {
                hs[j] = fmaf(hs[j], da, dtx * S1.Bv[j]);
                yv = fmaf(hs[j], S1.Cv[j], yv);
            }
            yv += __shfl_xor(yv, 32);
            if (half == 0)
                y[(rb + t + 1) * 512 + h * 32 + p] = f2bf(yv + Dh * S1.xv);
        }
    }
}

// ---------------------------------------------------------------------------
// normed = rmsnorm(y * silu(z), nw) over 512, f32 out. One wave/row, 8/lane.
// ---------------------------------------------------------------------------
__global__ __launch_bounds__(64) void gaterms_kernel(
    const bf16* __restrict__ y,      // 32768 x 512
    const bf16* __restrict__ zx,     // z = cols [0,512) of 32768 x 1104
    const float* __restrict__ nw,    // 512
    float* __restrict__ outp)        // 32768 x 512 (f32)
{
    int row = blockIdx.x, lane = threadIdx.x;
    union { uint4 u; bf16 b[8]; } yv, zv;
    yv.u = *(const uint4*)(y  + (size_t)row * 512  + lane * 8);
    zv.u = *(const uint4*)(zx + (size_t)row * 1104 + lane * 8);
    float4 nv0 = *(const float4*)(nw + lane * 8);
    float4 nv1 = *(const float4*)(nw + lane * 8 + 4);
    float nvv[8] = {nv0.x, nv0.y, nv0.z, nv0.w, nv1.x, nv1.y, nv1.z, nv1.w};
    float g[8]; float ss = 0.f;
#pragma unroll
    for (int i = 0; i < 8; ++i) {
        float gate = siluf(bf2f(zv.b[i]));
        g[i] = bf2f(yv.b[i]) * gate;
        ss += g[i] * g[i];
    }
#pragma unroll
    for (int o = 1; o < 64; o <<= 1) ss += __shfl_xor(ss, o);
    float rms = rsqrtf(ss * (1.f / 512.f) + EPSF);
    float* op = outp + (size_t)row * 512 + lane * 8;
    float4 o0 = {g[0]*rms*nvv[0], g[1]*rms*nvv[1], g[2]*rms*nvv[2], g[3]*rms*nvv[3]};
    float4 o1 = {g[4]*rms*nvv[4], g[5]*rms*nvv[5], g[6]*rms*nvv[6], g[7]*rms*nvv[7]};
    ((float4*)op)[0] = o0;
    ((float4*)op)[1] = o1;
}

// ---------------------------------------------------------------------------
// h = rmsnorm(mo + h, w) (f32 in/out). One wave per row, 4/lane.
// ---------------------------------------------------------------------------
__global__ __launch_bounds__(64) void resrms_kernel(
    const float* __restrict__ mo,    // 32768 x 256
    float* __restrict__ h,           // 32768 x 256 (in/out)
    const float* __restrict__ w)     // 256
{
    int row = blockIdx.x, lane = threadIdx.x;
    float4 a = *(const float4*)(mo + (size_t)row * 256 + lane * 4);
    float4 r = *(const float4*)(h  + (size_t)row * 256 + lane * 4);
    float s0 = a.x + r.x, s1 = a.y + r.y, s2 = a.z + r.z, s3 = a.w + r.w;
    float ss = s0 * s0 + s1 * s1 + s2 * s2 + s3 * s3;
#pragma unroll
    for (int o = 1; o < 64; o <<= 1) ss += __shfl_xor(ss, o);
    float rms = rsqrtf(ss * (1.f / 256.f) + EPSF);
    float4 wv = *(const float4*)(w + lane * 4);
    *(float4*)(h + (size_t)row * 256 + lane * 4) =
        (float4){s0 * rms * wv.x, s1 * rms * wv.y, s2 * rms * wv.z, s3 * rms * wv.w};
}

// ---------------------------------------------------------------------------
// layernorm over 256, f32 out. One wave per row, 4/lane.
// ---------------------------------------------------------------------------
__global__ __launch_bounds__(64) void ln_kernel(
    const float* __restrict__ x,     // 32768 x 256
    const float* __restrict__ w,     // 256
    const float* __restrict__ b,     // 256
    float* __restrict__ outp)        // 32768 x 256
{
    int row = blockIdx.x, lane = threadIdx.x;
    float4 v = *(const float4*)(x + (size_t)row * 256 + lane * 4);
    float sum = v.x + v.y + v.z + v.w;
    float sq  = v.x * v.x + v.y * v.y + v.z * v.z + v.w * v.w;
#pragma unroll
    for (int o = 1; o < 64; o <<= 1) { sum += __shfl_xor(sum, o); sq += __shfl_xor(sq, o); }
    float m  = sum * (1.f / 256.f);
    float var = sq * (1.f / 256.f) - m * m;
    float is = rsqrtf(var + EPSF);
    float4 wv = *(const float4*)(w + lane * 4);
    float4 bv = *(const float4*)(b + lane * 4);
    *(float4*)(outp + (size_t)row * 256 + lane * 4) = (float4){
        (v.x - m) * is * wv.x + bv.x,
        (v.y - m) * is * wv.y + bv.y,
        (v.z - m) * is * wv.z + bv.z,
        (v.w - m) * is * wv.w + bv.w};
}

// ---------------------------------------------------------------------------
extern "C" void kernel_launch(void* const* d_in, const int* in_sizes, int n_in,
                              void* d_out, int out_size, void* d_ws, size_t ws_size,
                              hipStream_t stream)
{
    const float* x      = (const float*)d_in[0];
    const float* ip_w   = (const float*)d_in[1];
    const float* ip_b   = (const float*)d_in[2];
    const float* m_inw  = (const float*)d_in[3];
    const float* m_inb  = (const float*)d_in[4];
    const float* m_convw= (const float*)d_in[5];
    const float* m_convb= (const float*)d_in[6];
    const float* m_dtb  = (const float*)d_in[7];
    const float* m_Alog = (const float*)d_in[8];
    const float* m_D    = (const float*)d_in[9];
    const float* m_nw   = (const float*)d_in[10];
    const float* m_outw = (const float*)d_in[11];
    const float* m_outb = (const float*)d_in[12];
    const float* rms_w  = (const float*)d_in[13];
    const float* ln1_w  = (const float*)d_in[14];
    const float* ln1_b  = (const float*)d_in[15];
    const float* w1     = (const float*)d_in[16];
    const float* b1     = (const float*)d_in[17];
    const float* w2     = (const float*)d_in[18];
    const float* b2     = (const float*)d_in[19];
    const float* ln2_w  = (const float*)d_in[20];
    const float* ln2_b  = (const float*)d_in[21];

    const int M = 32768;   // B * L
    char* wsb = (char*)d_ws;
    size_t off = 0;
    auto alloc = [&](size_t bytes) {
        void* p = wsb + off;
        off += (bytes + 255) & ~(size_t)255;
        return p;
    };
    // Region map (~219 MB total; lifetimes annotated):
    bf16*  zx   = (bf16*) alloc((size_t)M * 1104 * 2); // in_proj out; -> mo f32; -> gbuf f32
    float* h    = (float*)alloc((size_t)M * 256 * 4);  // residual stream (f32, whole run)
    float* U1   = (float*)alloc((size_t)M * 512 * 4);  // xs f32 -> normed f32 -> tb f32
    float* Bc   = (float*)alloc((size_t)M * 32 * 4);
    float* Cc   = (float*)alloc((size_t)M * 32 * 4);
    float* dtf  = (float*)alloc((size_t)M * 16 * 4);
    float* dAf  = (float*)alloc((size_t)M * 16 * 4);
    bf16*  ybuf = (bf16*) alloc((size_t)M * 512 * 2);  // y bf16 -> ubuf f32 (same bytes)
    (void)ws_size; (void)in_sizes; (void)n_in; (void)out_size;

    float* xs     = U1;
    float* normed = U1;
    float* tb     = U1;
    float* mo     = (float*)zx;
    float* gbuf   = (float*)zx;
    float* ubuf   = (float*)ybuf;

    dim3 blk(256);

    // G1: h = x @ ip_w + ip_b   (M x 1024) @ (1024 x 256)
    gemm_split<<<dim3(256, 4), blk, 0, stream>>>(
        x, 1024, ip_w, 256, ip_b, 256, 1024, h, 256, nullptr, 0, 0);

    for (int L = 0; L < 2; ++L) {
        const float* inw = m_inw  + (size_t)L * 256 * 1104;
        const float* inb = m_inb  + (size_t)L * 1104;
        const float* cw  = m_convw+ (size_t)L * 576 * 4;
        const float* cb  = m_convb+ (size_t)L * 576;
        const float* dtb = m_dtb  + L * 16;
        const float* Al  = m_Alog + L * 16;
        const float* Dv  = m_D    + L * 16;
        const float* nw  = m_nw   + (size_t)L * 512;
        const float* ow  = m_outw + (size_t)L * 512 * 256;
        const float* ob  = m_outb + (size_t)L * 256;
        const float* rw  = rms_w  + (size_t)L * 256;

        // in_proj: zx = h @ inw + inb   (M x 256) @ (256 x 1104), bf16 store
        gemm_split<<<dim3(256, 18), blk, 0, stream>>>(
            h, 256, inw, 1104, inb, 1104, 256, nullptr, 0, zx, 1104, 0);
        conv_kernel<<<dim3(M, 3), 192, 0, stream>>>(zx, cw, cb, xs, Bc, Cc);
        dtproj_kernel<<<M, 256, 0, stream>>>(h, inw, inb, dtb, Al, dtf, dAf);
        scan_kernel<<<256, 64, 0, stream>>>(xs, Bc, Cc, dtf, dAf, Dv, ybuf);
        gaterms_kernel<<<M, 64, 0, stream>>>(ybuf, zx, nw, normed);
        // out_proj: mo = normed @ outw + outb   (M x 512) @ (512 x 256)
        gemm_split<<<dim3(256, 4), blk, 0, stream>>>(
            normed, 512, ow, 256, ob, 256, 512, mo, 256, nullptr, 0, 0);
        resrms_kernel<<<M, 64, 0, stream>>>(mo, h, rw);
    }

    // MLP head
    ln_kernel<<<M, 64, 0, stream>>>(h, ln1_w, ln1_b, tb);
    gemm_split<<<dim3(256, 8), blk, 0, stream>>>(
        tb, 256, w1, 512, b1, 512, 256, gbuf, 512, nullptr, 0, 1);   // gelu
    gemm_split<<<dim3(256, 4), blk, 0, stream>>>(
        gbuf, 512, w2, 256, b2, 256, 512, ubuf, 256, nullptr, 0, 0);
    ln_kernel<<<M, 64, 0, stream>>>(ubuf, ln2_w, ln2_b, (float*)d_out);
}

// Round 4
// 1874.265 us; speedup vs baseline: 1.5128x; 1.5128x over previous
//
#include <hip/hip_runtime.h>

typedef __bf16 bf16;
typedef __bf16 bf16x8 __attribute__((ext_vector_type(8)));
typedef float  f32x4  __attribute__((ext_vector_type(4)));

#define EPSF 1e-5f

__device__ __forceinline__ float bf2f(bf16 x) { return (float)x; }
__device__ __forceinline__ bf16  f2bf(float x) { return (bf16)x; }
__device__ __forceinline__ float siluf(float x) { return x / (1.f + expf(-x)); }

// ---------------------------------------------------------------------------
// Split-bf16 MFMA GEMM: C[M,N] = A[M,K] @ W[K,N] + bias, A and W f32.
// Each operand is split v = hi + lo (hi = bf16(v), lo = bf16(v - hi));
// acc += aHi*bHi + aHi*bLo + aLo*bHi  (lo*lo dropped, rel err ~2^-16).
// Tile 128(M) x 64(N), BK=32, 256 thr = 4 waves (2M x 2N), each 64x32 via
// 4x2 frags of 16x16x32. M % 128 == 0; K % 32 == 0.
// ---------------------------------------------------------------------------
__global__ __launch_bounds__(256) void gemm_split(
    const float* __restrict__ A, int lda,
    const float* __restrict__ W, int ldw,
    const float* __restrict__ bias,
    int N, int K,
    float* __restrict__ outF, int ldF,
    bf16* __restrict__ outB, int ldB,
    int doGelu)
{
    __shared__ bf16 As [128][40];
    __shared__ bf16 Als[128][40];
    __shared__ bf16 Bs [64][40];
    __shared__ bf16 Bls[64][40];

    const int tid  = threadIdx.x;
    const int lane = tid & 63;
    const int wid  = tid >> 6;
    const int waveM = wid & 1, waveN = wid >> 1;
    const int m16 = lane & 15, quad = lane >> 4;
    const int row0 = blockIdx.x * 128;
    const int n0   = blockIdx.y * 64;

    f32x4 acc[4][2];
#pragma unroll
    for (int i = 0; i < 4; ++i)
#pragma unroll
        for (int j = 0; j < 2; ++j)
            acc[i][j] = (f32x4){0.f, 0.f, 0.f, 0.f};

    const int ar = tid >> 1, akc = (tid & 1) * 16;  // A staging: row, k-chunk
    const int bn = tid & 63, bk0 = tid >> 6;        // B staging: n, k base
    const bool nok = (n0 + bn) < N;

    for (int k0 = 0; k0 < K; k0 += 32) {
        // stage A tile 128x32 (f32 -> hi/lo bf16)
        {
            const float* asrc = A + (size_t)(row0 + ar) * lda + k0 + akc;
            bf16* dh = &As [ar][akc];
            bf16* dl = &Als[ar][akc];
#pragma unroll
            for (int c = 0; c < 4; ++c) {
                float4 f = ((const float4*)asrc)[c];
#pragma unroll
                for (int e = 0; e < 4; ++e) {
                    float v = (&f.x)[e];
                    bf16 hi = f2bf(v);
                    dh[c * 4 + e] = hi;
                    dl[c * 4 + e] = f2bf(v - bf2f(hi));
                }
            }
        }
        // stage B tile 32x64 (f32 strided -> hi/lo bf16, transposed Bs[n][k])
        {
            const float* wsrc = W + (size_t)k0 * ldw + n0 + bn;
#pragma unroll
            for (int it = 0; it < 8; ++it) {
                int k_l = bk0 + it * 4;
                float v = 0.f;
                if (nok) v = wsrc[(size_t)k_l * ldw];
                bf16 hi = f2bf(v);
                Bs [bn][k_l] = hi;
                Bls[bn][k_l] = f2bf(v - bf2f(hi));
            }
        }
        __syncthreads();

        bf16x8 aH[4], aL[4], bH[2], bL[2];
#pragma unroll
        for (int mi = 0; mi < 4; ++mi) {
            aH[mi] = *(const bf16x8*)&As [waveM * 64 + mi * 16 + m16][quad * 8];
            aL[mi] = *(const bf16x8*)&Als[waveM * 64 + mi * 16 + m16][quad * 8];
        }
#pragma unroll
        for (int ni = 0; ni < 2; ++ni) {
            bH[ni] = *(const bf16x8*)&Bs [waveN * 32 + ni * 16 + m16][quad * 8];
            bL[ni] = *(const bf16x8*)&Bls[waveN * 32 + ni * 16 + m16][quad * 8];
        }

#pragma unroll
        for (int mi = 0; mi < 4; ++mi)
#pragma unroll
            for (int ni = 0; ni < 2; ++ni) {
                acc[mi][ni] = __builtin_amdgcn_mfma_f32_16x16x32_bf16(
                    aH[mi], bH[ni], acc[mi][ni], 0, 0, 0);
                acc[mi][ni] = __builtin_amdgcn_mfma_f32_16x16x32_bf16(
                    aH[mi], bL[ni], acc[mi][ni], 0, 0, 0);
                acc[mi][ni] = __builtin_amdgcn_mfma_f32_16x16x32_bf16(
                    aL[mi], bH[ni], acc[mi][ni], 0, 0, 0);
            }
        __syncthreads();
    }

    // epilogue: D element (row = quad*4 + r, col = m16)
#pragma unroll
    for (int ni = 0; ni < 2; ++ni) {
        int col = n0 + waveN * 32 + ni * 16 + m16;
        if (col >= N) continue;
        float bv = bias ? bias[col] : 0.f;
#pragma unroll
        for (int mi = 0; mi < 4; ++mi) {
#pragma unroll
            for (int r = 0; r < 4; ++r) {
                int row = row0 + waveM * 64 + mi * 16 + quad * 4 + r;
                float v = acc[mi][ni][r] + bv;
                if (doGelu) v = 0.5f * v * (1.f + erff(v * 0.70710678118654752f));
                if (outB) outB[(size_t)row * ldB + col] = f2bf(v);
                if (outF) outF[(size_t)row * ldF + col] = v;
            }
        }
    }
}

// ---------------------------------------------------------------------------
// Causal depthwise conv (K=4) + bias + silu over xBC = zx[:, 512:1088].
// ---------------------------------------------------------------------------
__global__ __launch_bounds__(192) void conv_kernel(
    const bf16* __restrict__ zx,     // 32768 x 1104
    const float* __restrict__ cw,    // 576 x 4
    const float* __restrict__ cb,    // 576
    float* __restrict__ xs,          // 32768 x 512
    float* __restrict__ Bc,          // 32768 x 32
    float* __restrict__ Cc)          // 32768 x 32
{
    int row = blockIdx.x;
    int ch  = blockIdx.y * 192 + threadIdx.x;   // 0..575
    int l   = row & 2047;
    float acc = cb[ch];
#pragma unroll
    for (int i = 0; i < 4; ++i) {
        int ls = l + i - 3;
        if (ls >= 0)
            acc += bf2f(zx[(size_t)(row + i - 3) * 1104 + 512 + ch]) * cw[ch * 4 + i];
    }
    float s = siluf(acc);
    if (ch < 512)      xs[(size_t)row * 512 + ch]        = s;
    else if (ch < 544) Bc[(size_t)row * 32 + (ch - 512)] = s;
    else               Cc[(size_t)row * 32 + (ch - 544)] = s;
}

// ---------------------------------------------------------------------------
// Exact-f32 dt projection (see R2 comment). block = 256, one row per block.
// ---------------------------------------------------------------------------
__global__ __launch_bounds__(256) void dtproj_kernel(
    const float* __restrict__ h,      // 32768 x 256
    const float* __restrict__ inw,    // 256 x 1104
    const float* __restrict__ inb,    // 1104
    const float* __restrict__ dtbp,   // 16
    const float* __restrict__ Alog,   // 16
    float* __restrict__ dtf,          // 32768 x 16
    float* __restrict__ dAf)          // 32768 x 16
{
    __shared__ float wl[256][16];
    __shared__ float hl[256];
    __shared__ float red[16][17];
    int tid = threadIdx.x;
    int row = blockIdx.x;

    {
        const float* src = inw + (size_t)tid * 1104 + 1088;
        *(float4*)&wl[tid][0]  = ((const float4*)src)[0];
        *(float4*)&wl[tid][4]  = ((const float4*)src)[1];
        *(float4*)&wl[tid][8]  = ((const float4*)src)[2];
        *(float4*)&wl[tid][12] = ((const float4*)src)[3];
    }
    if (tid < 64)
        *(float4*)&hl[tid * 4] = *(const float4*)(h + (size_t)row * 256 + tid * 4);
    __syncthreads();

    int hh = tid >> 4, g = tid & 15;
    float s = 0.f;
#pragma unroll
    for (int i = 0; i < 16; ++i) {
        int k = g * 16 + i;
        s += hl[k] * wl[k][hh];
    }
    red[hh][g] = s;
    __syncthreads();

    if (tid < 16) {
        float tot = inb[1088 + tid];
#pragma unroll
        for (int i = 0; i < 16; ++i) tot += red[tid][i];
        float xx = tot + dtbp[tid];
        float sp = (xx > 20.f) ? xx : log1pf(expf(xx));
        float A  = -expf(Alog[tid]);
        dtf[(size_t)row * 16 + tid] = sp;
        dAf[(size_t)row * 16 + tid] = expf(sp * A);
    }
}

// ---------------------------------------------------------------------------
// Chunked SSM scan, Q=256, 8 chunks per (b,h).
// Lane layout: p = lane&31 (headdim), half = lane>>5, n in [16*half, +16).
// Phase 1: per chunk, local recurrence from h=0 -> end state E + decay P.
// Phase 2: per (b,h), sequential combine: Hstart_c = H; H = P_c*H + E_c
//          (in-place: cs[] E -> Hstart).
// Phase 3: per chunk, recurrence from Hstart, emit y.
// ---------------------------------------------------------------------------
#define QCH   256
#define NCH   8

struct StepB  { float Bv[16]; float da, dtv, xv; };
struct StepBC { float Bv[16]; float Cv[16]; float da, dtv, xv; };

__device__ __forceinline__ void load_stepB(
    StepB& S, const float* Bc, const float* dtf, const float* dAf,
    const float* xs, size_t r, int h, int p, int nb)
{
    const float4* bp = (const float4*)(Bc + r * 32 + nb);
    *(float4*)&S.Bv[0]  = bp[0];
    *(float4*)&S.Bv[4]  = bp[1];
    *(float4*)&S.Bv[8]  = bp[2];
    *(float4*)&S.Bv[12] = bp[3];
    S.da  = dAf[r * 16 + h];
    S.dtv = dtf[r * 16 + h];
    S.xv  = xs[r * 512 + h * 32 + p];
}

__device__ __forceinline__ void load_stepBC(
    StepBC& S, const float* Bc, const float* Cc, const float* dtf,
    const float* dAf, const float* xs, size_t r, int h, int p, int nb)
{
    const float4* bp = (const float4*)(Bc + r * 32 + nb);
    *(float4*)&S.Bv[0]  = bp[0];
    *(float4*)&S.Bv[4]  = bp[1];
    *(float4*)&S.Bv[8]  = bp[2];
    *(float4*)&S.Bv[12] = bp[3];
    const float4* cp = (const float4*)(Cc + r * 32 + nb);
    *(float4*)&S.Cv[0]  = cp[0];
    *(float4*)&S.Cv[4]  = cp[1];
    *(float4*)&S.Cv[8]  = cp[2];
    *(float4*)&S.Cv[12] = cp[3];
    S.da  = dAf[r * 16 + h];
    S.dtv = dtf[r * 16 + h];
    S.xv  = xs[r * 512 + h * 32 + p];
}

__global__ __launch_bounds__(64) void scan_phase1(
    const float* __restrict__ xs,   // 32768 x 512
    const float* __restrict__ Bc,   // 32768 x 32
    const float* __restrict__ dtf,  // 32768 x 16
    const float* __restrict__ dAf,  // 32768 x 16
    float* __restrict__ cs,         // 2048 x 1024 (chunk end states)
    float* __restrict__ cp)         // 2048 (chunk decay products)
{
    int blk = blockIdx.x;           // bh * NCH + c
    int bh = blk >> 3, c = blk & (NCH - 1);
    int b = bh >> 4, h = bh & 15;
    int lane = threadIdx.x;
    int p = lane & 31, half = lane >> 5, nb = half * 16;
    float hs[16];
#pragma unroll
    for (int j = 0; j < 16; ++j) hs[j] = 0.f;
    float P = 1.f;
    size_t rb = (size_t)b * 2048 + (size_t)c * QCH;

    StepB S0, S1;
    load_stepB(S0, Bc, dtf, dAf, xs, rb, h, p, nb);

    for (int t = 0; t < QCH; t += 2) {
        load_stepB(S1, Bc, dtf, dAf, xs, rb + t + 1, h, p, nb);
        {
            float dtx = S0.dtv * S0.xv, da = S0.da;
#pragma unroll
            for (int j = 0; j < 16; ++j)
                hs[j] = fmaf(hs[j], da, dtx * S0.Bv[j]);
            P *= da;
        }
        if (t + 2 < QCH)
            load_stepB(S0, Bc, dtf, dAf, xs, rb + t + 2, h, p, nb);
        {
            float dtx = S1.dtv * S1.xv, da = S1.da;
#pragma unroll
            for (int j = 0; j < 16; ++j)
                hs[j] = fmaf(hs[j], da, dtx * S1.Bv[j]);
            P *= da;
        }
    }

    float* dst = cs + (size_t)blk * 1024 + lane * 16;
#pragma unroll
    for (int q = 0; q < 4; ++q)
        ((float4*)dst)[q] = (float4){hs[q*4], hs[q*4+1], hs[q*4+2], hs[q*4+3]};
    if (lane == 0) cp[blk] = P;
}

__global__ __launch_bounds__(64) void scan_phase2(
    float* __restrict__ cs,         // 2048 x 1024, E -> Hstart in place
    const float* __restrict__ cp)   // 2048
{
    int bh = blockIdx.x;
    int lane = threadIdx.x;
    float H[16];
#pragma unroll
    for (int j = 0; j < 16; ++j) H[j] = 0.f;
    for (int c = 0; c < NCH; ++c) {
        float* base = cs + ((size_t)(bh * NCH + c)) * 1024 + lane * 16;
        float E[16];
#pragma unroll
        for (int q = 0; q < 4; ++q) {
            float4 v = ((const float4*)base)[q];
            E[q*4] = v.x; E[q*4+1] = v.y; E[q*4+2] = v.z; E[q*4+3] = v.w;
        }
        float P = cp[bh * NCH + c];
#pragma unroll
        for (int q = 0; q < 4; ++q)
            ((float4*)base)[q] = (float4){H[q*4], H[q*4+1], H[q*4+2], H[q*4+3]};
#pragma unroll
        for (int j = 0; j < 16; ++j)
            H[j] = fmaf(H[j], P, E[j]);
    }
}

__global__ __launch_bounds__(64) void scan_phase3(
    const float* __restrict__ xs,   // 32768 x 512
    const float* __restrict__ Bc,   // 32768 x 32
    const float* __restrict__ Cc,   // 32768 x 32
    const float* __restrict__ dtf,  // 32768 x 16
    const float* __restrict__ dAf,  // 32768 x 16
    const float* __restrict__ Dv,   // 16
    const float* __restrict__ cs,   // 2048 x 1024 (Hstart per chunk)
    bf16* __restrict__ y)           // 32768 x 512
{
    int blk = blockIdx.x;           // bh * NCH + c
    int bh = blk >> 3, c = blk & (NCH - 1);
    int b = bh >> 4, h = bh & 15;
    int lane = threadIdx.x;
    int p = lane & 31, half = lane >> 5, nb = half * 16;
    float Dh = Dv[h];
    float hs[16];
    {
        const float* src = cs + (size_t)blk * 1024 + lane * 16;
#pragma unroll
        for (int q = 0; q < 4; ++q) {
            float4 v = ((const float4*)src)[q];
            hs[q*4] = v.x; hs[q*4+1] = v.y; hs[q*4+2] = v.z; hs[q*4+3] = v.w;
        }
    }
    size_t rb = (size_t)b * 2048 + (size_t)c * QCH;

    StepBC S0, S1;
    load_stepBC(S0, Bc, Cc, dtf, dAf, xs, rb, h, p, nb);

    for (int t = 0; t < QCH; t += 2) {
        load_stepBC(S1, Bc, Cc, dtf, dAf, xs, rb + t + 1, h, p, nb);
        {
            float dtx = S0.dtv * S0.xv, da = S0.da, yv = 0.f;
#pragma unroll
            for (int j = 0; j < 16; ++j) {
                hs[j] = fmaf(hs[j], da, dtx * S0.Bv[j]);
                yv = fmaf(hs[j], S0.Cv[j], yv);
            }
            yv += __shfl_xor(yv, 32);
            if (half == 0)
                y[(rb + t) * 512 + h * 32 + p] = f2bf(yv + Dh * S0.xv);
        }
        if (t + 2 < QCH)
            load_stepBC(S0, Bc, Cc, dtf, dAf, xs, rb + t + 2, h, p, nb);
        {
            float dtx = S1.dtv * S1.xv, da = S1.da, yv = 0.f;
#pragma unroll
            for (int j = 0; j < 16; ++j) {
                hs[j] = fmaf(hs[j], da, dtx * S1.Bv[j]);
                yv = fmaf(hs[j], S1.Cv[j], yv);
            }
            yv += __shfl_xor(yv, 32);
            if (half == 0)
                y[(rb + t + 1) * 512 + h * 32 + p] = f2bf(yv + Dh * S1.xv);
        }
    }
}

// ---------------------------------------------------------------------------
// normed = rmsnorm(y * silu(z), nw) over 512, f32 out. One wave/row, 8/lane.
// ---------------------------------------------------------------------------
__global__ __launch_bounds__(64) void gaterms_kernel(
    const bf16* __restrict__ y,      // 32768 x 512
    const bf16* __restrict__ zx,     // z = cols [0,512) of 32768 x 1104
    const float* __restrict__ nw,    // 512
    float* __restrict__ outp)        // 32768 x 512 (f32)
{
    int row = blockIdx.x, lane = threadIdx.x;
    union { uint4 u; bf16 b[8]; } yv, zv;
    yv.u = *(const uint4*)(y  + (size_t)row * 512  + lane * 8);
    zv.u = *(const uint4*)(zx + (size_t)row * 1104 + lane * 8);
    float4 nv0 = *(const float4*)(nw + lane * 8);
    float4 nv1 = *(const float4*)(nw + lane * 8 + 4);
    float nvv[8] = {nv0.x, nv0.y, nv0.z, nv0.w, nv1.x, nv1.y, nv1.z, nv1.w};
    float g[8]; float ss = 0.f;
#pragma unroll
    for (int i = 0; i < 8; ++i) {
        float gate = siluf(bf2f(zv.b[i]));
        g[i] = bf2f(yv.b[i]) * gate;
        ss += g[i] * g[i];
    }
#pragma unroll
    for (int o = 1; o < 64; o <<= 1) ss += __shfl_xor(ss, o);
    float rms = rsqrtf(ss * (1.f / 512.f) + EPSF);
    float* op = outp + (size_t)row * 512 + lane * 8;
    ((float4*)op)[0] = (float4){g[0]*rms*nvv[0], g[1]*rms*nvv[1], g[2]*rms*nvv[2], g[3]*rms*nvv[3]};
    ((float4*)op)[1] = (float4){g[4]*rms*nvv[4], g[5]*rms*nvv[5], g[6]*rms*nvv[6], g[7]*rms*nvv[7]};
}

// ---------------------------------------------------------------------------
// h = rmsnorm(mo + h, w) (f32 in/out). One wave per row, 4/lane.
// ---------------------------------------------------------------------------
__global__ __launch_bounds__(64) void resrms_kernel(
    const float* __restrict__ mo,    // 32768 x 256
    float* __restrict__ h,           // 32768 x 256 (in/out)
    const float* __restrict__ w)     // 256
{
    int row = blockIdx.x, lane = threadIdx.x;
    float4 a = *(const float4*)(mo + (size_t)row * 256 + lane * 4);
    float4 r = *(const float4*)(h  + (size_t)row * 256 + lane * 4);
    float s0 = a.x + r.x, s1 = a.y + r.y, s2 = a.z + r.z, s3 = a.w + r.w;
    float ss = s0 * s0 + s1 * s1 + s2 * s2 + s3 * s3;
#pragma unroll
    for (int o = 1; o < 64; o <<= 1) ss += __shfl_xor(ss, o);
    float rms = rsqrtf(ss * (1.f / 256.f) + EPSF);
    float4 wv = *(const float4*)(w + lane * 4);
    *(float4*)(h + (size_t)row * 256 + lane * 4) =
        (float4){s0 * rms * wv.x, s1 * rms * wv.y, s2 * rms * wv.z, s3 * rms * wv.w};
}

// ---------------------------------------------------------------------------
// layernorm over 256, f32 out. One wave per row, 4/lane.
// ---------------------------------------------------------------------------
__global__ __launch_bounds__(64) void ln_kernel(
    const float* __restrict__ x,     // 32768 x 256
    const float* __restrict__ w,     // 256
    const float* __restrict__ b,     // 256
    float* __restrict__ outp)        // 32768 x 256
{
    int row = blockIdx.x, lane = threadIdx.x;
    float4 v = *(const float4*)(x + (size_t)row * 256 + lane * 4);
    float sum = v.x + v.y + v.z + v.w;
    float sq  = v.x * v.x + v.y * v.y + v.z * v.z + v.w * v.w;
#pragma unroll
    for (int o = 1; o < 64; o <<= 1) { sum += __shfl_xor(sum, o); sq += __shfl_xor(sq, o); }
    float m  = sum * (1.f / 256.f);
    float var = sq * (1.f / 256.f) - m * m;
    float is = rsqrtf(var + EPSF);
    float4 wv = *(const float4*)(w + lane * 4);
    float4 bv = *(const float4*)(b + lane * 4);
    *(float4*)(outp + (size_t)row * 256 + lane * 4) = (float4){
        (v.x - m) * is * wv.x + bv.x,
        (v.y - m) * is * wv.y + bv.y,
        (v.z - m) * is * wv.z + bv.z,
        (v.w - m) * is * wv.w + bv.w};
}

// ---------------------------------------------------------------------------
extern "C" void kernel_launch(void* const* d_in, const int* in_sizes, int n_in,
                              void* d_out, int out_size, void* d_ws, size_t ws_size,
                              hipStream_t stream)
{
    const float* x      = (const float*)d_in[0];
    const float* ip_w   = (const float*)d_in[1];
    const float* ip_b   = (const float*)d_in[2];
    const float* m_inw  = (const float*)d_in[3];
    const float* m_inb  = (const float*)d_in[4];
    const float* m_convw= (const float*)d_in[5];
    const float* m_convb= (const float*)d_in[6];
    const float* m_dtb  = (const float*)d_in[7];
    const float* m_Alog = (const float*)d_in[8];
    const float* m_D    = (const float*)d_in[9];
    const float* m_nw   = (const float*)d_in[10];
    const float* m_outw = (const float*)d_in[11];
    const float* m_outb = (const float*)d_in[12];
    const float* rms_w  = (const float*)d_in[13];
    const float* ln1_w  = (const float*)d_in[14];
    const float* ln1_b  = (const float*)d_in[15];
    const float* w1     = (const float*)d_in[16];
    const float* b1     = (const float*)d_in[17];
    const float* w2     = (const float*)d_in[18];
    const float* b2     = (const float*)d_in[19];
    const float* ln2_w  = (const float*)d_in[20];
    const float* ln2_b  = (const float*)d_in[21];

    const int M = 32768;   // B * L
    char* wsb = (char*)d_ws;
    size_t off = 0;
    auto alloc = [&](size_t bytes) {
        void* p = wsb + off;
        off += (bytes + 255) & ~(size_t)255;
        return p;
    };
    // Region map (~228 MB total):
    bf16*  zx   = (bf16*) alloc((size_t)M * 1104 * 2); // in_proj out; -> mo f32; -> gbuf f32
    float* h    = (float*)alloc((size_t)M * 256 * 4);  // residual stream (f32)
    float* U1   = (float*)alloc((size_t)M * 512 * 4);  // xs f32 -> normed f32 -> tb f32
    float* Bc   = (float*)alloc((size_t)M * 32 * 4);
    float* Cc   = (float*)alloc((size_t)M * 32 * 4);
    float* dtf  = (float*)alloc((size_t)M * 16 * 4);
    float* dAf  = (float*)alloc((size_t)M * 16 * 4);
    bf16*  ybuf = (bf16*) alloc((size_t)M * 512 * 2);  // y bf16 -> ubuf f32
    float* cs   = (float*)alloc((size_t)2048 * 1024 * 4); // chunk states (8.4 MB)
    float* cpb  = (float*)alloc((size_t)2048 * 4);
    (void)ws_size; (void)in_sizes; (void)n_in; (void)out_size;

    float* xs     = U1;
    float* normed = U1;
    float* tb     = U1;
    float* mo     = (float*)zx;
    float* gbuf   = (float*)zx;
    float* ubuf   = (float*)ybuf;

    dim3 blk(256);

    // G1: h = x @ ip_w + ip_b   (M x 1024) @ (1024 x 256)
    gemm_split<<<dim3(256, 4), blk, 0, stream>>>(
        x, 1024, ip_w, 256, ip_b, 256, 1024, h, 256, nullptr, 0, 0);

    for (int L = 0; L < 2; ++L) {
        const float* inw = m_inw  + (size_t)L * 256 * 1104;
        const float* inb = m_inb  + (size_t)L * 1104;
        const float* cw  = m_convw+ (size_t)L * 576 * 4;
        const float* cb  = m_convb+ (size_t)L * 576;
        const float* dtb = m_dtb  + L * 16;
        const float* Al  = m_Alog + L * 16;
        const float* Dv  = m_D    + L * 16;
        const float* nw  = m_nw   + (size_t)L * 512;
        const float* ow  = m_outw + (size_t)L * 512 * 256;
        const float* ob  = m_outb + (size_t)L * 256;
        const float* rw  = rms_w  + (size_t)L * 256;

        // in_proj: zx = h @ inw + inb   (M x 256) @ (256 x 1104), bf16 store
        gemm_split<<<dim3(256, 18), blk, 0, stream>>>(
            h, 256, inw, 1104, inb, 1104, 256, nullptr, 0, zx, 1104, 0);
        conv_kernel<<<dim3(M, 3), 192, 0, stream>>>(zx, cw, cb, xs, Bc, Cc);
        dtproj_kernel<<<M, 256, 0, stream>>>(h, inw, inb, dtb, Al, dtf, dAf);
        scan_phase1<<<2048, 64, 0, stream>>>(xs, Bc, dtf, dAf, cs, cpb);
        scan_phase2<<<256, 64, 0, stream>>>(cs, cpb);
        scan_phase3<<<2048, 64, 0, stream>>>(xs, Bc, Cc, dtf, dAf, Dv, cs, ybuf);
        gaterms_kernel<<<M, 64, 0, stream>>>(ybuf, zx, nw, normed);
        // out_proj: mo = normed @ outw + outb   (M x 512) @ (512 x 256)
        gemm_split<<<dim3(256, 4), blk, 0, stream>>>(
            normed, 512, ow, 256, ob, 256, 512, mo, 256, nullptr, 0, 0);
        resrms_kernel<<<M, 64, 0, stream>>>(mo, h, rw);
    }

    // MLP head
    ln_kernel<<<M, 64, 0, stream>>>(h, ln1_w, ln1_b, tb);
    gemm_split<<<dim3(256, 8), blk, 0, stream>>>(
        tb, 256, w1, 512, b1, 512, 256, gbuf, 512, nullptr, 0, 1);   // gelu
    gemm_split<<<dim3(256, 4), blk, 0, stream>>>(
        gbuf, 512, w2, 256, b2, 256, 512, ubuf, 256, nullptr, 0, 0);
    ln_kernel<<<M, 64, 0, stream>>>(ubuf, ln2_w, ln2_b, (float*)d_out);
}

// Round 5
// 1526.679 us; speedup vs baseline: 1.8572x; 1.2277x over previous
//
#include <hip/hip_runtime.h>

typedef __bf16 bf16;
typedef __bf16 bf16x8 __attribute__((ext_vector_type(8)));
typedef float  f32x4  __attribute__((ext_vector_type(4)));

#define EPSF 1e-5f

__device__ __forceinline__ float bf2f(bf16 x) { return (float)x; }
__device__ __forceinline__ bf16  f2bf(float x) { return (bf16)x; }
__device__ __forceinline__ float siluf(float x) { return x / (1.f + expf(-x)); }

// ---------------------------------------------------------------------------
// Weight prepack: W[K][N] f32 -> WT_hi[N][K], WT_lo[N][K] bf16 (hi/lo split).
// 7 segments in one launch (grid.y = segment).
// ---------------------------------------------------------------------------
struct PrepackArgs {
    const float* W[7];
    bf16* TH[7];
    bf16* TL[7];
    int K[7];
    int N[7];
};

__global__ __launch_bounds__(256) void prepack_kernel(PrepackArgs a)
{
    int s = blockIdx.y;
    int idx = blockIdx.x * 256 + threadIdx.x;
    int K = a.K[s], N = a.N[s];
    if (idx >= K * N) return;
    int k = idx / N, n = idx - k * N;
    float v = a.W[s][idx];
    bf16 hi = f2bf(v);
    a.TH[s][(size_t)n * K + k] = hi;
    a.TL[s][(size_t)n * K + k] = f2bf(v - bf2f(hi));
}

// ---------------------------------------------------------------------------
// Split-bf16 MFMA GEMM, restructured:
//  - A: either hi/lo bf16 planes (AH/AL) or f32 (Af) converted in staging.
//  - B: prepacked transposed hi/lo bf16 (WTh/WTl, [N][K]) loaded straight
//    from global into fragments (L2-resident), next-tile prefetched.
//  - acc += aH*bH + aH*bL + aL*bH  (lo*lo dropped, rel ~2^-16).
//  - Epilogue: bias, optional exact gelu; writes f32 / bf16 / hi+lo planes;
//    optional fused dt path (cols >= 1088): softplus -> dtf, exp(dt*A) -> dAf.
// Tile 128(M) x 64(N), BK=32, 256 thr = 4 waves (2M x 2N).
// ---------------------------------------------------------------------------
__global__ __launch_bounds__(256) void gemm_hl(
    const bf16* __restrict__ AH, const bf16* __restrict__ AL,
    const float* __restrict__ Af, int lda,
    const bf16* __restrict__ WTh, const bf16* __restrict__ WTl,
    const float* __restrict__ bias,
    int N, int K,
    float* __restrict__ outF, int ldF,
    bf16* __restrict__ outB, int ldB,
    bf16* __restrict__ outH, bf16* __restrict__ outL, int ldH,
    int doGelu,
    const float* __restrict__ dtb, const float* __restrict__ Alog,
    float* __restrict__ dtf, float* __restrict__ dAf)
{
    __shared__ bf16 As [128][40];
    __shared__ bf16 Als[128][40];

    const int tid  = threadIdx.x;
    const int lane = tid & 63;
    const int wid  = tid >> 6;
    const int waveM = wid & 1, waveN = wid >> 1;
    const int m16 = lane & 15, quad = lane >> 4;
    const int row0 = blockIdx.x * 128;
    const int n0   = blockIdx.y * 64;

    f32x4 acc[4][2];
#pragma unroll
    for (int i = 0; i < 4; ++i)
#pragma unroll
        for (int j = 0; j < 2; ++j)
            acc[i][j] = (f32x4){0.f, 0.f, 0.f, 0.f};

    const int ar = tid >> 1, akc = (tid & 1) * 16;  // A staging: row, k-chunk

    // B fragment source rows (clamped so OOB tiles read valid memory;
    // results for col >= N are discarded in the epilogue).
    const int bn0 = min(n0 + waveN * 32 + m16,      N - 1);
    const int bn1 = min(n0 + waveN * 32 + 16 + m16, N - 1);
    const bf16* bH0p = WTh + (size_t)bn0 * K + quad * 8;
    const bf16* bH1p = WTh + (size_t)bn1 * K + quad * 8;
    const bf16* bL0p = WTl + (size_t)bn0 * K + quad * 8;
    const bf16* bL1p = WTl + (size_t)bn1 * K + quad * 8;

    bf16x8 bH[2], bL[2], bHn[2], bLn[2];
    bH[0] = *(const bf16x8*)(bH0p);
    bH[1] = *(const bf16x8*)(bH1p);
    bL[0] = *(const bf16x8*)(bL0p);
    bL[1] = *(const bf16x8*)(bL1p);

    for (int k0 = 0; k0 < K; k0 += 32) {
        // ---- stage A tile 128x32 (hi/lo planes or f32->split) ----
        if (AH) {
            const bf16* s0 = AH + (size_t)(row0 + ar) * lda + k0 + akc;
            const bf16* s1 = AL + (size_t)(row0 + ar) * lda + k0 + akc;
            *(uint4*)&As [ar][akc]     = *(const uint4*)s0;
            *(uint4*)&As [ar][akc + 8] = *(const uint4*)(s0 + 8);
            *(uint4*)&Als[ar][akc]     = *(const uint4*)s1;
            *(uint4*)&Als[ar][akc + 8] = *(const uint4*)(s1 + 8);
        } else {
            const float* asrc = Af + (size_t)(row0 + ar) * lda + k0 + akc;
            bf16* dh = &As [ar][akc];
            bf16* dl = &Als[ar][akc];
#pragma unroll
            for (int c = 0; c < 4; ++c) {
                float4 f = ((const float4*)asrc)[c];
#pragma unroll
                for (int e = 0; e < 4; ++e) {
                    float v = (&f.x)[e];
                    bf16 hi = f2bf(v);
                    dh[c * 4 + e] = hi;
                    dl[c * 4 + e] = f2bf(v - bf2f(hi));
                }
            }
        }
        __syncthreads();

        // ---- prefetch next k-tile's B fragments (global, L2-hot) ----
        const bool more = (k0 + 32) < K;
        if (more) {
            int kn = k0 + 32;
            bHn[0] = *(const bf16x8*)(bH0p + kn);
            bHn[1] = *(const bf16x8*)(bH1p + kn);
            bLn[0] = *(const bf16x8*)(bL0p + kn);
            bLn[1] = *(const bf16x8*)(bL1p + kn);
        }

        // ---- LDS -> A fragments ----
        bf16x8 aH[4], aL[4];
#pragma unroll
        for (int mi = 0; mi < 4; ++mi) {
            aH[mi] = *(const bf16x8*)&As [waveM * 64 + mi * 16 + m16][quad * 8];
            aL[mi] = *(const bf16x8*)&Als[waveM * 64 + mi * 16 + m16][quad * 8];
        }

#pragma unroll
        for (int mi = 0; mi < 4; ++mi)
#pragma unroll
            for (int ni = 0; ni < 2; ++ni) {
                acc[mi][ni] = __builtin_amdgcn_mfma_f32_16x16x32_bf16(
                    aH[mi], bH[ni], acc[mi][ni], 0, 0, 0);
                acc[mi][ni] = __builtin_amdgcn_mfma_f32_16x16x32_bf16(
                    aH[mi], bL[ni], acc[mi][ni], 0, 0, 0);
                acc[mi][ni] = __builtin_amdgcn_mfma_f32_16x16x32_bf16(
                    aL[mi], bH[ni], acc[mi][ni], 0, 0, 0);
            }
        __syncthreads();

        if (more) {
            bH[0] = bHn[0]; bH[1] = bHn[1];
            bL[0] = bLn[0]; bL[1] = bLn[1];
        }
    }

    // ---- epilogue: D element (row = quad*4 + r, col = m16) ----
#pragma unroll
    for (int ni = 0; ni < 2; ++ni) {
        int col = n0 + waveN * 32 + ni * 16 + m16;
        if (col >= N) continue;
        float bv = bias ? bias[col] : 0.f;
#pragma unroll
        for (int mi = 0; mi < 4; ++mi) {
#pragma unroll
            for (int r = 0; r < 4; ++r) {
                int row = row0 + waveM * 64 + mi * 16 + quad * 4 + r;
                float v = acc[mi][ni][r] + bv;
                if (dtf && col >= 1088) {
                    int head = col - 1088;
                    float xx = v + dtb[head];
                    float sp = (xx > 20.f) ? xx : log1pf(expf(xx));
                    float A  = -expf(Alog[head]);
                    dtf[(size_t)row * 16 + head] = sp;
                    dAf[(size_t)row * 16 + head] = expf(sp * A);
                } else {
                    if (doGelu) v = 0.5f * v * (1.f + erff(v * 0.70710678118654752f));
                    if (outB) outB[(size_t)row * ldB + col] = f2bf(v);
                    if (outF) outF[(size_t)row * ldF + col] = v;
                    if (outH) {
                        bf16 hi = f2bf(v);
                        outH[(size_t)row * ldH + col] = hi;
                        outL[(size_t)row * ldH + col] = f2bf(v - bf2f(hi));
                    }
                }
            }
        }
    }
}

// ---------------------------------------------------------------------------
// Causal depthwise conv (K=4) + bias + silu over xBC = zx[:, 512:1088].
// ---------------------------------------------------------------------------
__global__ __launch_bounds__(192) void conv_kernel(
    const bf16* __restrict__ zx,     // 32768 x 1104
    const float* __restrict__ cw,    // 576 x 4
    const float* __restrict__ cb,    // 576
    float* __restrict__ xs,          // 32768 x 512
    float* __restrict__ Bc,          // 32768 x 32
    float* __restrict__ Cc)          // 32768 x 32
{
    int row = blockIdx.x;
    int ch  = blockIdx.y * 192 + threadIdx.x;   // 0..575
    int l   = row & 2047;
    float acc = cb[ch];
#pragma unroll
    for (int i = 0; i < 4; ++i) {
        int ls = l + i - 3;
        if (ls >= 0)
            acc += bf2f(zx[(size_t)(row + i - 3) * 1104 + 512 + ch]) * cw[ch * 4 + i];
    }
    float s = siluf(acc);
    if (ch < 512)      xs[(size_t)row * 512 + ch]        = s;
    else if (ch < 544) Bc[(size_t)row * 32 + (ch - 512)] = s;
    else               Cc[(size_t)row * 32 + (ch - 544)] = s;
}

// ---------------------------------------------------------------------------
// Chunked SSM scan, Q=256, 8 chunks per (b,h). See R3 comment.
// ---------------------------------------------------------------------------
#define QCH   256
#define NCH   8

struct StepB  { float Bv[16]; float da, dtv, xv; };
struct StepBC { float Bv[16]; float Cv[16]; float da, dtv, xv; };

__device__ __forceinline__ void load_stepB(
    StepB& S, const float* Bc, const float* dtf, const float* dAf,
    const float* xs, size_t r, int h, int p, int nb)
{
    const float4* bp = (const float4*)(Bc + r * 32 + nb);
    *(float4*)&S.Bv[0]  = bp[0];
    *(float4*)&S.Bv[4]  = bp[1];
    *(float4*)&S.Bv[8]  = bp[2];
    *(float4*)&S.Bv[12] = bp[3];
    S.da  = dAf[r * 16 + h];
    S.dtv = dtf[r * 16 + h];
    S.xv  = xs[r * 512 + h * 32 + p];
}

__device__ __forceinline__ void load_stepBC(
    StepBC& S, const float* Bc, const float* Cc, const float* dtf,
    const float* dAf, const float* xs, size_t r, int h, int p, int nb)
{
    const float4* bp = (const float4*)(Bc + r * 32 + nb);
    *(float4*)&S.Bv[0]  = bp[0];
    *(float4*)&S.Bv[4]  = bp[1];
    *(float4*)&S.Bv[8]  = bp[2];
    *(float4*)&S.Bv[12] = bp[3];
    const float4* cp = (const float4*)(Cc + r * 32 + nb);
    *(float4*)&S.Cv[0]  = cp[0];
    *(float4*)&S.Cv[4]  = cp[1];
    *(float4*)&S.Cv[8]  = cp[2];
    *(float4*)&S.Cv[12] = cp[3];
    S.da  = dAf[r * 16 + h];
    S.dtv = dtf[r * 16 + h];
    S.xv  = xs[r * 512 + h * 32 + p];
}

__global__ __launch_bounds__(64) void scan_phase1(
    const float* __restrict__ xs,
    const float* __restrict__ Bc,
    const float* __restrict__ dtf,
    const float* __restrict__ dAf,
    float* __restrict__ cs,         // 2048 x 1024
    float* __restrict__ cp)         // 2048
{
    int blk = blockIdx.x;
    int bh = blk >> 3, c = blk & (NCH - 1);
    int b = bh >> 4, h = bh & 15;
    int lane = threadIdx.x;
    int p = lane & 31, half = lane >> 5, nb = half * 16;
    float hs[16];
#pragma unroll
    for (int j = 0; j < 16; ++j) hs[j] = 0.f;
    float P = 1.f;
    size_t rb = (size_t)b * 2048 + (size_t)c * QCH;

    StepB S0, S1;
    load_stepB(S0, Bc, dtf, dAf, xs, rb, h, p, nb);

    for (int t = 0; t < QCH; t += 2) {
        load_stepB(S1, Bc, dtf, dAf, xs, rb + t + 1, h, p, nb);
        {
            float dtx = S0.dtv * S0.xv, da = S0.da;
#pragma unroll
            for (int j = 0; j < 16; ++j)
                hs[j] = fmaf(hs[j], da, dtx * S0.Bv[j]);
            P *= da;
        }
        if (t + 2 < QCH)
            load_stepB(S0, Bc, dtf, dAf, xs, rb + t + 2, h, p, nb);
        {
            float dtx = S1.dtv * S1.xv, da = S1.da;
#pragma unroll
            for (int j = 0; j < 16; ++j)
                hs[j] = fmaf(hs[j], da, dtx * S1.Bv[j]);
            P *= da;
        }
    }

    float* dst = cs + (size_t)blk * 1024 + lane * 16;
#pragma unroll
    for (int q = 0; q < 4; ++q)
        ((float4*)dst)[q] = (float4){hs[q*4], hs[q*4+1], hs[q*4+2], hs[q*4+3]};
    if (lane == 0) cp[blk] = P;
}

__global__ __launch_bounds__(64) void scan_phase2(
    float* __restrict__ cs,
    const float* __restrict__ cp)
{
    int bh = blockIdx.x;
    int lane = threadIdx.x;
    float H[16];
#pragma unroll
    for (int j = 0; j < 16; ++j) H[j] = 0.f;
    for (int c = 0; c < NCH; ++c) {
        float* base = cs + ((size_t)(bh * NCH + c)) * 1024 + lane * 16;
        float E[16];
#pragma unroll
        for (int q = 0; q < 4; ++q) {
            float4 v = ((const float4*)base)[q];
            E[q*4] = v.x; E[q*4+1] = v.y; E[q*4+2] = v.z; E[q*4+3] = v.w;
        }
        float P = cp[bh * NCH + c];
#pragma unroll
        for (int q = 0; q < 4; ++q)
            ((float4*)base)[q] = (float4){H[q*4], H[q*4+1], H[q*4+2], H[q*4+3]};
#pragma unroll
        for (int j = 0; j < 16; ++j)
            H[j] = fmaf(H[j], P, E[j]);
    }
}

__global__ __launch_bounds__(64) void scan_phase3(
    const float* __restrict__ xs,
    const float* __restrict__ Bc,
    const float* __restrict__ Cc,
    const float* __restrict__ dtf,
    const float* __restrict__ dAf,
    const float* __restrict__ Dv,
    const float* __restrict__ cs,
    bf16* __restrict__ y)
{
    int blk = blockIdx.x;
    int bh = blk >> 3, c = blk & (NCH - 1);
    int b = bh >> 4, h = bh & 15;
    int lane = threadIdx.x;
    int p = lane & 31, half = lane >> 5, nb = half * 16;
    float Dh = Dv[h];
    float hs[16];
    {
        const float* src = cs + (size_t)blk * 1024 + lane * 16;
#pragma unroll
        for (int q = 0; q < 4; ++q) {
            float4 v = ((const float4*)src)[q];
            hs[q*4] = v.x; hs[q*4+1] = v.y; hs[q*4+2] = v.z; hs[q*4+3] = v.w;
        }
    }
    size_t rb = (size_t)b * 2048 + (size_t)c * QCH;

    StepBC S0, S1;
    load_stepBC(S0, Bc, Cc, dtf, dAf, xs, rb, h, p, nb);

    for (int t = 0; t < QCH; t += 2) {
        load_stepBC(S1, Bc, Cc, dtf, dAf, xs, rb + t + 1, h, p, nb);
        {
            float dtx = S0.dtv * S0.xv, da = S0.da, yv = 0.f;
#pragma unroll
            for (int j = 0; j < 16; ++j) {
                hs[j] = fmaf(hs[j], da, dtx * S0.Bv[j]);
                yv = fmaf(hs[j], S0.Cv[j], yv);
            }
            yv += __shfl_xor(yv, 32);
            if (half == 0)
                y[(rb + t) * 512 + h * 32 + p] = f2bf(yv + Dh * S0.xv);
        }
        if (t + 2 < QCH)
            load_stepBC(S0, Bc, Cc, dtf, dAf, xs, rb + t + 2, h, p, nb);
        {
            float dtx = S1.dtv * S1.xv, da = S1.da, yv = 0.f;
#pragma unroll
            for (int j = 0; j < 16; ++j) {
                hs[j] = fmaf(hs[j], da, dtx * S1.Bv[j]);
                yv = fmaf(hs[j], S1.Cv[j], yv);
            }
            yv += __shfl_xor(yv, 32);
            if (half == 0)
                y[(rb + t + 1) * 512 + h * 32 + p] = f2bf(yv + Dh * S1.xv);
        }
    }
}

// ---------------------------------------------------------------------------
// normed = rmsnorm(y * silu(z), nw) over 512 -> hi/lo bf16 planes.
// ---------------------------------------------------------------------------
__global__ __launch_bounds__(64) void gaterms_kernel(
    const bf16* __restrict__ y,      // 32768 x 512
    const bf16* __restrict__ zx,     // z = cols [0,512) of 32768 x 1104
    const float* __restrict__ nw,    // 512
    bf16* __restrict__ outH,         // 32768 x 512
    bf16* __restrict__ outL)         // 32768 x 512
{
    int row = blockIdx.x, lane = threadIdx.x;
    union { uint4 u; bf16 b[8]; } yv, zv, oh, ol;
    yv.u = *(const uint4*)(y  + (size_t)row * 512  + lane * 8);
    zv.u = *(const uint4*)(zx + (size_t)row * 1104 + lane * 8);
    float4 nv0 = *(const float4*)(nw + lane * 8);
    float4 nv1 = *(const float4*)(nw + lane * 8 + 4);
    float nvv[8] = {nv0.x, nv0.y, nv0.z, nv0.w, nv1.x, nv1.y, nv1.z, nv1.w};
    float g[8]; float ss = 0.f;
#pragma unroll
    for (int i = 0; i < 8; ++i) {
        float gate = siluf(bf2f(zv.b[i]));
        g[i] = bf2f(yv.b[i]) * gate;
        ss += g[i] * g[i];
    }
#pragma unroll
    for (int o = 1; o < 64; o <<= 1) ss += __shfl_xor(ss, o);
    float rms = rsqrtf(ss * (1.f / 512.f) + EPSF);
#pragma unroll
    for (int i = 0; i < 8; ++i) {
        float v = g[i] * rms * nvv[i];
        bf16 hi = f2bf(v);
        oh.b[i] = hi;
        ol.b[i] = f2bf(v - bf2f(hi));
    }
    *(uint4*)(outH + (size_t)row * 512 + lane * 8) = oh.u;
    *(uint4*)(outL + (size_t)row * 512 + lane * 8) = ol.u;
}

// ---------------------------------------------------------------------------
// h = rmsnorm(mo + h, w) (f32 in/out). One wave per row, 4/lane.
// ---------------------------------------------------------------------------
__global__ __launch_bounds__(64) void resrms_kernel(
    const float* __restrict__ mo,
    float* __restrict__ h,
    const float* __restrict__ w)
{
    int row = blockIdx.x, lane = threadIdx.x;
    float4 a = *(const float4*)(mo + (size_t)row * 256 + lane * 4);
    float4 r = *(const float4*)(h  + (size_t)row * 256 + lane * 4);
    float s0 = a.x + r.x, s1 = a.y + r.y, s2 = a.z + r.z, s3 = a.w + r.w;
    float ss = s0 * s0 + s1 * s1 + s2 * s2 + s3 * s3;
#pragma unroll
    for (int o = 1; o < 64; o <<= 1) ss += __shfl_xor(ss, o);
    float rms = rsqrtf(ss * (1.f / 256.f) + EPSF);
    float4 wv = *(const float4*)(w + lane * 4);
    *(float4*)(h + (size_t)row * 256 + lane * 4) =
        (float4){s0 * rms * wv.x, s1 * rms * wv.y, s2 * rms * wv.z, s3 * rms * wv.w};
}

// ---------------------------------------------------------------------------
// layernorm over 256 -> hi/lo planes and/or f32. One wave per row, 4/lane.
// ---------------------------------------------------------------------------
__global__ __launch_bounds__(64) void ln_kernel(
    const float* __restrict__ x,
    const float* __restrict__ w,
    const float* __restrict__ b,
    bf16* __restrict__ outH,
    bf16* __restrict__ outL,
    float* __restrict__ outF)
{
    int row = blockIdx.x, lane = threadIdx.x;
    float4 v = *(const float4*)(x + (size_t)row * 256 + lane * 4);
    float sum = v.x + v.y + v.z + v.w;
    float sq  = v.x * v.x + v.y * v.y + v.z * v.z + v.w * v.w;
#pragma unroll
    for (int o = 1; o < 64; o <<= 1) { sum += __shfl_xor(sum, o); sq += __shfl_xor(sq, o); }
    float m  = sum * (1.f / 256.f);
    float var = sq * (1.f / 256.f) - m * m;
    float is = rsqrtf(var + EPSF);
    float4 wv = *(const float4*)(w + lane * 4);
    float4 bv = *(const float4*)(b + lane * 4);
    float o0 = (v.x - m) * is * wv.x + bv.x;
    float o1 = (v.y - m) * is * wv.y + bv.y;
    float o2 = (v.z - m) * is * wv.z + bv.z;
    float o3 = (v.w - m) * is * wv.w + bv.w;
    if (outH) {
        union { uint2 u; bf16 bb[4]; } oh, ol;
        float o[4] = {o0, o1, o2, o3};
#pragma unroll
        for (int i = 0; i < 4; ++i) {
            bf16 hi = f2bf(o[i]);
            oh.bb[i] = hi;
            ol.bb[i] = f2bf(o[i] - bf2f(hi));
        }
        *(uint2*)(outH + (size_t)row * 256 + lane * 4) = oh.u;
        *(uint2*)(outL + (size_t)row * 256 + lane * 4) = ol.u;
    }
    if (outF)
        *(float4*)(outF + (size_t)row * 256 + lane * 4) = (float4){o0, o1, o2, o3};
}

// ---------------------------------------------------------------------------
extern "C" void kernel_launch(void* const* d_in, const int* in_sizes, int n_in,
                              void* d_out, int out_size, void* d_ws, size_t ws_size,
                              hipStream_t stream)
{
    const float* x      = (const float*)d_in[0];
    const float* ip_w   = (const float*)d_in[1];
    const float* ip_b   = (const float*)d_in[2];
    const float* m_inw  = (const float*)d_in[3];
    const float* m_inb  = (const float*)d_in[4];
    const float* m_convw= (const float*)d_in[5];
    const float* m_convb= (const float*)d_in[6];
    const float* m_dtb  = (const float*)d_in[7];
    const float* m_Alog = (const float*)d_in[8];
    const float* m_D    = (const float*)d_in[9];
    const float* m_nw   = (const float*)d_in[10];
    const float* m_outw = (const float*)d_in[11];
    const float* m_outb = (const float*)d_in[12];
    const float* rms_w  = (const float*)d_in[13];
    const float* ln1_w  = (const float*)d_in[14];
    const float* ln1_b  = (const float*)d_in[15];
    const float* w1     = (const float*)d_in[16];
    const float* b1     = (const float*)d_in[17];
    const float* w2     = (const float*)d_in[18];
    const float* b2     = (const float*)d_in[19];
    const float* ln2_w  = (const float*)d_in[20];
    const float* ln2_b  = (const float*)d_in[21];

    const int M = 32768;   // B * L
    char* wsb = (char*)d_ws;
    size_t off = 0;
    auto alloc = [&](size_t bytes) {
        void* p = wsb + off;
        off += (bytes + 255) & ~(size_t)255;
        return p;
    };
    // ---- activations (~227 MB incl. weights) ----
    bf16*  zx   = (bf16*) alloc((size_t)M * 1104 * 2); // zx bf16 -> mo f32 -> g planes
    float* h    = (float*)alloc((size_t)M * 256 * 4);  // residual stream f32
    float* U1   = (float*)alloc((size_t)M * 512 * 4);  // xs f32 -> normed planes -> tb planes
    float* Bc   = (float*)alloc((size_t)M * 32 * 4);
    float* Cc   = (float*)alloc((size_t)M * 32 * 4);
    float* dtf  = (float*)alloc((size_t)M * 16 * 4);
    float* dAf  = (float*)alloc((size_t)M * 16 * 4);
    bf16*  ybuf = (bf16*) alloc((size_t)M * 512 * 2);  // y bf16 -> ubuf f32
    float* cs   = (float*)alloc((size_t)2048 * 1024 * 4);
    float* cpb  = (float*)alloc((size_t)2048 * 4);
    // ---- prepacked weights (hi/lo, transposed [N][K]) ----
    bf16* ipTH   = (bf16*)alloc(262144 * 2);
    bf16* ipTL   = (bf16*)alloc(262144 * 2);
    bf16* inwTH0 = (bf16*)alloc(282624 * 2);
    bf16* inwTL0 = (bf16*)alloc(282624 * 2);
    bf16* inwTH1 = (bf16*)alloc(282624 * 2);
    bf16* inwTL1 = (bf16*)alloc(282624 * 2);
    bf16* outwTH0= (bf16*)alloc(131072 * 2);
    bf16* outwTL0= (bf16*)alloc(131072 * 2);
    bf16* outwTH1= (bf16*)alloc(131072 * 2);
    bf16* outwTL1= (bf16*)alloc(131072 * 2);
    bf16* w1TH   = (bf16*)alloc(131072 * 2);
    bf16* w1TL   = (bf16*)alloc(131072 * 2);
    bf16* w2TH   = (bf16*)alloc(131072 * 2);
    bf16* w2TL   = (bf16*)alloc(131072 * 2);
    (void)ws_size; (void)in_sizes; (void)n_in; (void)out_size;

    float* xs      = U1;
    bf16*  normedH = (bf16*)U1;
    bf16*  normedL = normedH + (size_t)M * 512;
    bf16*  tbH     = (bf16*)U1;
    bf16*  tbL     = tbH + (size_t)M * 256;
    float* mo      = (float*)zx;
    bf16*  gH      = (bf16*)zx;
    bf16*  gL      = gH + (size_t)M * 512;
    float* ubuf    = (float*)ybuf;

    // ---- prepack all weights (one launch, 7 segments) ----
    PrepackArgs pa;
    pa.W[0] = ip_w;               pa.TH[0] = ipTH;    pa.TL[0] = ipTL;    pa.K[0] = 1024; pa.N[0] = 256;
    pa.W[1] = m_inw;              pa.TH[1] = inwTH0;  pa.TL[1] = inwTL0;  pa.K[1] = 256;  pa.N[1] = 1104;
    pa.W[2] = m_inw + 256*1104;   pa.TH[2] = inwTH1;  pa.TL[2] = inwTL1;  pa.K[2] = 256;  pa.N[2] = 1104;
    pa.W[3] = m_outw;             pa.TH[3] = outwTH0; pa.TL[3] = outwTL0; pa.K[3] = 512;  pa.N[3] = 256;
    pa.W[4] = m_outw + 512*256;   pa.TH[4] = outwTH1; pa.TL[4] = outwTL1; pa.K[4] = 512;  pa.N[4] = 256;
    pa.W[5] = w1;                 pa.TH[5] = w1TH;    pa.TL[5] = w1TL;    pa.K[5] = 256;  pa.N[5] = 512;
    pa.W[6] = w2;                 pa.TH[6] = w2TH;    pa.TL[6] = w2TL;    pa.K[6] = 512;  pa.N[6] = 256;
    prepack_kernel<<<dim3(1104, 7), 256, 0, stream>>>(pa);

    dim3 blk(256);

    // G1: h = x @ ip_w + ip_b   (M x 1024) @ (1024 x 256), f32-A path
    gemm_hl<<<dim3(256, 4), blk, 0, stream>>>(
        nullptr, nullptr, x, 1024, ipTH, ipTL, ip_b, 256, 1024,
        h, 256, nullptr, 0, nullptr, nullptr, 0, 0,
        nullptr, nullptr, nullptr, nullptr);

    for (int L = 0; L < 2; ++L) {
        const bf16* inwTH = L ? inwTH1 : inwTH0;
        const bf16* inwTL = L ? inwTL1 : inwTL0;
        const bf16* outwTH= L ? outwTH1 : outwTH0;
        const bf16* outwTL= L ? outwTL1 : outwTL0;
        const float* inb = m_inb  + (size_t)L * 1104;
        const float* cw  = m_convw+ (size_t)L * 576 * 4;
        const float* cb  = m_convb+ (size_t)L * 576;
        const float* dtb = m_dtb  + L * 16;
        const float* Al  = m_Alog + L * 16;
        const float* Dv  = m_D    + L * 16;
        const float* nw  = m_nw   + (size_t)L * 512;
        const float* ob  = m_outb + (size_t)L * 256;
        const float* rw  = rms_w  + (size_t)L * 256;

        // in_proj: zx = h @ inw + inb (f32-A), fused dt: cols 1088+ -> dtf/dAf
        gemm_hl<<<dim3(256, 18), blk, 0, stream>>>(
            nullptr, nullptr, h, 256, inwTH, inwTL, inb, 1104, 256,
            nullptr, 0, zx, 1104, nullptr, nullptr, 0, 0,
            dtb, Al, dtf, dAf);
        conv_kernel<<<dim3(M, 3), 192, 0, stream>>>(zx, cw, cb, xs, Bc, Cc);
        scan_phase1<<<2048, 64, 0, stream>>>(xs, Bc, dtf, dAf, cs, cpb);
        scan_phase2<<<256, 64, 0, stream>>>(cs, cpb);
        scan_phase3<<<2048, 64, 0, stream>>>(xs, Bc, Cc, dtf, dAf, Dv, cs, ybuf);
        gaterms_kernel<<<M, 64, 0, stream>>>(ybuf, zx, nw, normedH, normedL);
        // out_proj: mo = normed @ outw + outb (plane-A)
        gemm_hl<<<dim3(256, 4), blk, 0, stream>>>(
            normedH, normedL, nullptr, 512, outwTH, outwTL, ob, 256, 512,
            mo, 256, nullptr, 0, nullptr, nullptr, 0, 0,
            nullptr, nullptr, nullptr, nullptr);
        resrms_kernel<<<M, 64, 0, stream>>>(mo, h, rw);
    }

    // MLP head
    ln_kernel<<<M, 64, 0, stream>>>(h, ln1_w, ln1_b, tbH, tbL, nullptr);
    gemm_hl<<<dim3(256, 8), blk, 0, stream>>>(
        tbH, tbL, nullptr, 256, w1TH, w1TL, b1, 512, 256,
        nullptr, 0, nullptr, 0, gH, gL, 512, 1,
        nullptr, nullptr, nullptr, nullptr);
    gemm_hl<<<dim3(256, 4), blk, 0, stream>>>(
        gH, gL, nullptr, 512, w2TH, w2TL, b2, 256, 512,
        ubuf, 256, nullptr, 0, nullptr, nullptr, 0, 0,
        nullptr, nullptr, nullptr, nullptr);
    ln_kernel<<<M, 64, 0, stream>>>(ubuf, ln2_w, ln2_b, nullptr, nullptr, (float*)d_out);
}